// Round 2
// baseline (247765.112 us; speedup 1.0000x reference)
//
#include <hip/hip_runtime.h>
#include <math.h>

// Problem constants
#define NN 1024
#define MM 64
#define CC 512
#define LL 64
#define TT 8192
#define EPSF 1e-16f

// Flat output offsets (return order: seq_out, ww_h, rw_h, a_h, r_h)
#define OFF_SEQ 0
#define OFF_WW  (TT*LL)
#define OFF_RW  (OFF_WW + TT*NN)
#define OFF_A   (OFF_RW + TT*NN)
#define OFF_R   (OFF_A + TT*MM)

// d_ws float offsets
#define WSF_PRE   0
#define WSF_M     (TT*CC)
#define WSF_WCAT  (WSF_M + 32768)      // 512*272 packed [Ww | Wr | 0pad]

__device__ __forceinline__ float sigmoid_f(float x) { return 1.0f / (1.0f + __expf(-x)); }
__device__ __forceinline__ float softplus_f(float x) { return (x > 15.0f) ? x : __logf(1.0f + __expf(x)); }
__device__ __forceinline__ float tanh_f(float x) { float e = __expf(2.0f * x); return 1.0f - 2.0f / (e + 1.0f); }
__device__ __forceinline__ float pow_f(float b, float g) { return __expf(g * __logf(b)); }  // b >= 0
__device__ __forceinline__ int bitrev4(int l) {
    return ((l & 1) << 3) | ((l & 2) << 1) | ((l & 4) >> 1) | ((l & 8) >> 3);
}

// Kernel 1: pre[t][j] = sum_i seq[t][i] * Wc[i][j] + bc[j]
__global__ void pre_kernel(const float* __restrict__ seq, const float* __restrict__ Wc,
                           const float* __restrict__ bc, float* __restrict__ pre) {
    int gid = blockIdx.x * blockDim.x + threadIdx.x;
    int t = gid >> 9;
    int j = gid & 511;
    if (t >= TT) return;
    const float* s = seq + t * LL;
    float acc = bc[j];
    #pragma unroll 8
    for (int i = 0; i < LL; ++i) acc += s[i] * Wc[i * CC + j];
    pre[gid] = acc;
}

// Kernel 1b: Wcat[512][272] = [Ww (198 cols) | Wr (70 cols) | 4 zero cols]
__global__ void pack_kernel(const float* __restrict__ Ww, const float* __restrict__ Wr,
                            float* __restrict__ Wcat) {
    int gid = blockIdx.x * 256 + threadIdx.x;
    if (gid >= 512 * 272) return;
    int r = gid / 272, c = gid - r * 272;
    float v = 0.0f;
    if (c < 198) v = Ww[r * 198 + c];
    else if (c < 268) v = Wr[r * 70 + (c - 198)];
    Wcat[gid] = v;
}

// Persistent single workgroup.
// Round-9 changes (latency-serialization theory; all bitwise-order-preserving):
//  - __launch_bounds__(1024, 4): 16 waves = 4 waves/EU is forced by block size anyway,
//    so raise the VGPR cap 64 -> 128. Round 0/1 showed VGPR_Count=64 with 64+ floats of
//    persistent state -> compiler was shuffling Mlo/mh through AGPR/scratch.
//  - Phase A weights are step-invariant: rows 8q..8q+3 hoisted into 4 persistent float4
//    regs (loaded once); rows 8q+4..8q+7 prefetched each step during phase J (live range
//    J->A only, dead at the phase-I register peak). Phase A has no exposed L2 latency.
//  - Phase C head prefetch: first 4 Wcat rows issued right after barrier 1 so the
//    pipeline ramp (~250cy L2 latency) hides under phase B. Same accumulation order.
//  - Wcat LDS staging removed (round-1: neutral-to-negative, +75% bank conflicts).
__global__ __launch_bounds__(1024, 4)
void ntm_kernel(
    const float* __restrict__ pre,   // [TT][CC]
    const float* __restrict__ Wc,    // [128][512]
    const float* __restrict__ Wcat,  // [512][272] packed Ww|Wr
    const float* __restrict__ br,    // [70]
    const float* __restrict__ bw,    // [198]
    const float* __restrict__ Wo,    // [64][64]
    const float* __restrict__ bo,    // [64]
    float* __restrict__ out)
{
    __shared__ __align__(16) float sh_part[4096];     // A: 8x512 ; C: 8x272
    __shared__ __align__(16) float sh_h[CC];
    __shared__ __align__(16) float sh_kw[MM];
    __shared__ __align__(16) float sh_kr[MM];
    __shared__ __align__(16) float sh_e[MM];
    __shared__ __align__(16) float sh_a[MM];
    __shared__ __align__(16) float sh_scal[16];
    __shared__ __align__(16) float sh_evbuf[NN];
    __shared__ __align__(16) float sh_wpbuf[NN];
    __shared__ __align__(16) float red[4][16];
    __shared__ __align__(16) float wmat[16][MM];
    __shared__ __align__(16) float sh_r[MM];
    __shared__ __align__(16) float sh_Wo[MM * LL];
    __shared__ __align__(16) float sh_bo[LL];
    __shared__ __align__(16) float sh_bw[200];
    __shared__ __align__(16) float sh_br[72];
    __shared__ __align__(16) float sh_pren[CC];       // prefetched pre[t+1]

    const int tid  = threadIdx.x;
    const int lane = tid & 63;
    const int wv   = tid >> 6;

    // ---- preload constants into LDS, init state ----
    for (int i = tid; i < MM * LL; i += NN) sh_Wo[i] = Wo[i];
    if (tid < LL)  sh_bo[tid] = bo[tid];
    if (tid < 198) sh_bw[tid] = bw[tid];
    if (tid < 70)  sh_br[tid] = br[tid];
    if (tid < MM)  sh_r[tid] = 1e-6f;
    if (tid < CC)  sh_pren[tid] = pre[tid];

    // Phase-A geometry + persistent weights (rows 8q..8q+3 of Wc2, step-invariant)
    const int gA = tid & 127, qA = tid >> 7;
    const float4* wbaseA = (const float4*)(Wc + (64 + qA * 8) * CC) + gA;
    float4 wA[4];
    #pragma unroll
    for (int i = 0; i < 4; ++i) wA[i] = wbaseA[i * 128];
    float4 wAd[4];                                     // rows 8q+4..8q+7, refreshed in J
    #pragma unroll
    for (int i = 0; i < 4; ++i) wAd[i] = wbaseA[(4 + i) * 128];

    // Phase-C geometry
    const int gC = tid % 68, qC = tid / 68;           // valid when tid < 544
    const float4* wbaseC = (const float4*)(Wcat + (qC * 64) * 272) + gC;

    float Mlo[32];
    #pragma unroll
    for (int j = 0; j < 32; ++j) Mlo[j] = 1e-6f;
    float4 mh[8];
    #pragma unroll
    for (int k = 0; k < 8; ++k) mh[k] = make_float4(1e-6f, 1e-6f, 1e-6f, 1e-6f);
    float rown = sqrtf(64.0f * 1e-12f);
    float wwprev = (tid == NN / 2) ? 1.0f : 0.0f;
    float rwprev = wwprev;
    __syncthreads();

    for (int t = 0; t < TT; ++t) {
        // ===== A: h-partials; weights from persistent regs (no L2 exposure) =====
        {
            float4 acc = make_float4(0.0f, 0.0f, 0.0f, 0.0f);
            #pragma unroll
            for (int i = 0; i < 4; ++i) {
                float rv = sh_r[qA * 8 + i];
                acc.x += rv * wA[i].x; acc.y += rv * wA[i].y;
                acc.z += rv * wA[i].z; acc.w += rv * wA[i].w;
            }
            #pragma unroll
            for (int i = 0; i < 4; ++i) {
                float rv = sh_r[qA * 8 + 4 + i];
                acc.x += rv * wAd[i].x; acc.y += rv * wAd[i].y;
                acc.z += rv * wAd[i].z; acc.w += rv * wAd[i].w;
            }
            ((float4*)sh_part)[qA * 128 + gA] = acc;  // sh_part[q*512 + 4g]
        }
        __syncthreads();  // 1
        // ===== B: h = tanh(pre + 8 partials); C-head prefetch issues first =====
        float4 cpre[4];
        if (tid < 544) {
            #pragma unroll
            for (int i = 0; i < 4; ++i) cpre[i] = wbaseC[i * 68];
        }
        if (tid < CC) {
            float p0 = sh_part[tid]          + sh_part[512 + tid];
            float p1 = sh_part[1024 + tid]   + sh_part[1536 + tid];
            float p2 = sh_part[2048 + tid]   + sh_part[2560 + tid];
            float p3 = sh_part[3072 + tid]   + sh_part[3584 + tid];
            float v = sh_pren[tid] + ((p0 + p1) + (p2 + p3));
            sh_h[tid] = tanh_f(v);
        }
        __syncthreads();  // 2
        // ===== C: ow/orr partials; i=0..3 from prefetched regs, 4..63 stream =====
        if (tid < 544) {
            const float* hq = sh_h + qC * 64;
            float4 acc = make_float4(0.0f, 0.0f, 0.0f, 0.0f);
            #pragma unroll
            for (int i = 0; i < 4; ++i) {
                float hv = hq[i];
                acc.x += hv * cpre[i].x; acc.y += hv * cpre[i].y;
                acc.z += hv * cpre[i].z; acc.w += hv * cpre[i].w;
            }
            #pragma unroll 8
            for (int i = 4; i < 64; ++i) {
                float hv = hq[i];
                float4 w = wbaseC[i * 68];            // next row: +272 floats = +68 float4
                acc.x += hv * w.x; acc.y += hv * w.y;
                acc.z += hv * w.z; acc.w += hv * w.w;
            }
            ((float4*)sh_part)[qC * 68 + gC] = acc;   // sh_part[q*272 + 4g]
        }
        __syncthreads();  // 3
        // ===== D: head transforms, ow folded inline from 8 partials (+ pre prefetch) =====
        #define OWV(c) ( (((sh_part[(c)] + sh_part[272 + (c)]) + (sh_part[544 + (c)] + sh_part[816 + (c)])) \
                        + ((sh_part[1088 + (c)] + sh_part[1360 + (c)]) + (sh_part[1632 + (c)] + sh_part[1904 + (c)]))) \
                        + ((c) < 198 ? sh_bw[(c)] : sh_br[(c) - 198]) )
        if (wv == 0) {
            float v = tanh_f(OWV(lane));
            sh_kw[lane] = v;
            float s2 = v * v;
            #pragma unroll
            for (int m = 1; m < 64; m <<= 1) s2 += __shfl_xor(s2, m, 64);
            if (lane == 0) sh_scal[6] = sqrtf(s2);
        } else if (wv == 1) {
            float v = tanh_f(OWV(198 + lane));
            sh_kr[lane] = v;
            float s2 = v * v;
            #pragma unroll
            for (int m = 1; m < 64; m <<= 1) s2 += __shfl_xor(s2, m, 64);
            if (lane == 0) sh_scal[14] = sqrtf(s2);
        } else if (wv == 2) {
            sh_e[lane] = sigmoid_f(OWV(70 + lane));
        } else if (wv == 3) {
            float v = tanh_f(OWV(134 + lane));
            sh_a[lane] = v;
            out[OFF_A + t * MM + lane] = v;
        } else if (wv == 4) {
            if (lane == 0) {
                sh_scal[0] = softplus_f(OWV(64));
                sh_scal[1] = sigmoid_f(OWV(65));
                float x0 = OWV(66), x1 = OWV(67), x2 = OWV(68);
                float mx = fmaxf(x0, fmaxf(x1, x2));
                float e0 = __expf(x0 - mx), e1 = __expf(x1 - mx), e2 = __expf(x2 - mx);
                float ss = e0 + e1 + e2;
                sh_scal[2] = e0 / ss; sh_scal[3] = e1 / ss; sh_scal[4] = e2 / ss;
                sh_scal[5] = 1.0f + softplus_f(OWV(69));
            }
        } else if (wv == 5) {
            if (lane == 0) {
                sh_scal[8] = softplus_f(OWV(198 + 64));
                sh_scal[9] = sigmoid_f(OWV(198 + 65));
                float x0 = OWV(198 + 66), x1 = OWV(198 + 67), x2 = OWV(198 + 68);
                float mx = fmaxf(x0, fmaxf(x1, x2));
                float e0 = __expf(x0 - mx), e1 = __expf(x1 - mx), e2 = __expf(x2 - mx);
                float ss = e0 + e1 + e2;
                sh_scal[10] = e0 / ss; sh_scal[11] = e1 / ss; sh_scal[12] = e2 / ss;
                sh_scal[13] = 1.0f + softplus_f(OWV(198 + 69));
            }
        } else if (wv >= 6 && wv < 14) {     // prefetch pre[t+1] into LDS (512 idle threads)
            if (t + 1 < TT) sh_pren[tid - 384] = pre[(t + 1) * CC + (tid - 384)];
        }
        #undef OWV
        __syncthreads();  // 4

        // ===== E: write-head dot + ev =====
        float betaW = sh_scal[0], gW = sh_scal[1];
        float s0W = sh_scal[2], s1W = sh_scal[3], s2W = sh_scal[4];
        float gamW = sh_scal[5], knW = sh_scal[6];
        {
            const float4* k4 = (const float4*)sh_kw;
            float d0 = 0.0f, d1 = 0.0f, d2 = 0.0f, d3 = 0.0f;
            #pragma unroll
            for (int j4 = 0; j4 < 8; ++j4) {
                float4 k = k4[j4];
                d0 += Mlo[4*j4]   * k.x;
                d1 += Mlo[4*j4+1] * k.y;
                d2 += Mlo[4*j4+2] * k.z;
                d3 += Mlo[4*j4+3] * k.w;
            }
            #pragma unroll
            for (int k8 = 0; k8 < 8; ++k8) {
                float4 k = k4[8 + k8];
                d0 += mh[k8].x * k.x;
                d1 += mh[k8].y * k.y;
                d2 += mh[k8].z * k.z;
                d3 += mh[k8].w * k.w;
            }
            float dot = (d0 + d1) + (d2 + d3);
            float sim = dot / (rown * knW + EPSF);
            float ev = __expf(betaW * sim);
            sh_evbuf[tid] = ev;
            sh_wpbuf[tid] = wwprev;
            float s = ev;
            #pragma unroll
            for (int m = 1; m < 64; m <<= 1) s += __shfl_xor(s, m, 64);
            if (lane == 0) red[0][wv] = s;
        }
        __syncthreads();  // 5
        // ===== F: conv + sharpen (write) =====
        float wshW;
        {
            const float4* rp = (const float4*)red[0];
            float Sev = 0.0f;
            #pragma unroll
            for (int w4 = 0; w4 < 4; ++w4) { float4 p = rp[w4]; Sev += p.x + p.y + p.z + p.w; }
            int tm1 = (tid + NN - 1) & (NN - 1), tp1 = (tid + 1) & (NN - 1);
            float cEV = s0W * sh_evbuf[tm1] + s1W * sh_evbuf[tid] + s2W * sh_evbuf[tp1];
            float cWP = s0W * sh_wpbuf[tm1] + s1W * sh_wpbuf[tid] + s2W * sh_wpbuf[tp1];
            float ws = (gW / Sev) * cEV + (1.0f - gW) * cWP;
            wshW = pow_f(ws, gamW);
            float s = wshW;
            #pragma unroll
            for (int m = 1; m < 64; m <<= 1) s += __shfl_xor(s, m, 64);
            if (lane == 0) red[1][wv] = s;
        }
        __syncthreads();  // 6
        // ===== G: normalize wwn; M update + norm =====
        {
            const float4* rp = (const float4*)red[1];
            float Swsh = 0.0f;
            #pragma unroll
            for (int w4 = 0; w4 < 4; ++w4) { float4 p = rp[w4]; Swsh += p.x + p.y + p.z + p.w; }
            float wwn = wshW / (Swsh + EPSF);
            out[OFF_WW + t * NN + tid] = wwn;
            wwprev = wwn;
            const float4* e4p = (const float4*)sh_e;
            const float4* a4p = (const float4*)sh_a;
            float n0 = 0.0f, n1 = 0.0f, n2 = 0.0f, n3 = 0.0f;
            #pragma unroll
            for (int j4 = 0; j4 < 8; ++j4) {
                float4 e = e4p[j4], a = a4p[j4];
                float m0 = Mlo[4*j4]   * (1.0f - wwn * e.x) + wwn * a.x;
                float m1 = Mlo[4*j4+1] * (1.0f - wwn * e.y) + wwn * a.y;
                float m2 = Mlo[4*j4+2] * (1.0f - wwn * e.z) + wwn * a.z;
                float m3 = Mlo[4*j4+3] * (1.0f - wwn * e.w) + wwn * a.w;
                Mlo[4*j4] = m0; Mlo[4*j4+1] = m1; Mlo[4*j4+2] = m2; Mlo[4*j4+3] = m3;
                n0 += m0 * m0; n1 += m1 * m1; n2 += m2 * m2; n3 += m3 * m3;
            }
            #pragma unroll
            for (int k = 0; k < 8; ++k) {
                float4 e = e4p[8 + k], a = a4p[8 + k];
                float4 m = mh[k];
                m.x = m.x * (1.0f - wwn * e.x) + wwn * a.x;
                m.y = m.y * (1.0f - wwn * e.y) + wwn * a.y;
                m.z = m.z * (1.0f - wwn * e.z) + wwn * a.z;
                m.w = m.w * (1.0f - wwn * e.w) + wwn * a.w;
                mh[k] = m;
                n0 += m.x * m.x; n1 += m.y * m.y; n2 += m.z * m.z; n3 += m.w * m.w;
            }
            rown = sqrtf((n0 + n1) + (n2 + n3));
        }

        // ===== H: read-head dot + ev =====
        float betaR = sh_scal[8], gR = sh_scal[9];
        float s0R = sh_scal[10], s1R = sh_scal[11], s2R = sh_scal[12];
        float gamR = sh_scal[13], knR = sh_scal[14];
        {
            const float4* k4 = (const float4*)sh_kr;
            float d0 = 0.0f, d1 = 0.0f, d2 = 0.0f, d3 = 0.0f;
            #pragma unroll
            for (int j4 = 0; j4 < 8; ++j4) {
                float4 k = k4[j4];
                d0 += Mlo[4*j4]   * k.x;
                d1 += Mlo[4*j4+1] * k.y;
                d2 += Mlo[4*j4+2] * k.z;
                d3 += Mlo[4*j4+3] * k.w;
            }
            #pragma unroll
            for (int k8 = 0; k8 < 8; ++k8) {
                float4 k = k4[8 + k8];
                d0 += mh[k8].x * k.x;
                d1 += mh[k8].y * k.y;
                d2 += mh[k8].z * k.z;
                d3 += mh[k8].w * k.w;
            }
            float dot = (d0 + d1) + (d2 + d3);
            float sim = dot / (rown * knR + EPSF);
            float ev = __expf(betaR * sim);
            sh_evbuf[tid] = ev;
            sh_wpbuf[tid] = rwprev;
            float s = ev;
            #pragma unroll
            for (int m = 1; m < 64; m <<= 1) s += __shfl_xor(s, m, 64);
            if (lane == 0) red[2][wv] = s;
        }
        __syncthreads();  // 7
        // ===== I: conv + sharpen (read); transpose partials =====
        float wshR;
        {
            const float4* rp = (const float4*)red[2];
            float Sev = 0.0f;
            #pragma unroll
            for (int w4 = 0; w4 < 4; ++w4) { float4 p = rp[w4]; Sev += p.x + p.y + p.z + p.w; }
            int tm1 = (tid + NN - 1) & (NN - 1), tp1 = (tid + 1) & (NN - 1);
            float cEV = s0R * sh_evbuf[tm1] + s1R * sh_evbuf[tid] + s2R * sh_evbuf[tp1];
            float cWP = s0R * sh_wpbuf[tm1] + s1R * sh_wpbuf[tid] + s2R * sh_wpbuf[tp1];
            float ws = (gR / Sev) * cEV + (1.0f - gR) * cWP;
            wshR = pow_f(ws, gamR);
            float s = wshR;
            #pragma unroll
            for (int m = 1; m < 64; m <<= 1) s += __shfl_xor(s, m, 64);
            if (lane == 0) red[3][wv] = s;
            #pragma unroll
            for (int chunk = 0; chunk < 4; ++chunk) {
                const int cb = chunk * 16;
                float v[16];
                if (chunk < 2) {
                    #pragma unroll
                    for (int i = 0; i < 16; ++i) v[i] = wshR * Mlo[chunk * 16 + i];
                } else {
                    #pragma unroll
                    for (int k = 0; k < 4; ++k) {
                        float4 m = mh[(chunk - 2) * 4 + k];
                        v[4*k]   = wshR * m.x;
                        v[4*k+1] = wshR * m.y;
                        v[4*k+2] = wshR * m.z;
                        v[4*k+3] = wshR * m.w;
                    }
                }
                #pragma unroll
                for (int st = 0; st < 4; ++st) {
                    const int m = 1 << st;
                    const int hs = 8 >> st;
                    bool hi = (lane & m) != 0;
                    #pragma unroll
                    for (int i = 0; i < 8; ++i) {
                        if (i < hs) {
                            float send = hi ? v[i] : v[i + hs];
                            float recv = __shfl_xor(send, m, 64);
                            float keep = hi ? v[i + hs] : v[i];
                            v[i] = keep + recv;
                        }
                    }
                }
                float v0 = v[0];
                v0 += __shfl_xor(v0, 16, 64);
                v0 += __shfl_xor(v0, 32, 64);
                if (lane < 16) wmat[wv][cb + bitrev4(lane)] = v0;
            }
        }
        __syncthreads();  // 8
        // ===== J: prefetch next-step A-weights; normalize rwn + finalize =====
        {
            #pragma unroll
            for (int i = 0; i < 4; ++i) wAd[i] = wbaseA[(4 + i) * 128];  // static values; hides A's L2 latency
            const float4* rp = (const float4*)red[3];
            float Swsh = 0.0f;
            #pragma unroll
            for (int w4 = 0; w4 < 4; ++w4) { float4 p = rp[w4]; Swsh += p.x + p.y + p.z + p.w; }
            float inv = 1.0f / (Swsh + EPSF);
            float rwn = wshR * inv;
            out[OFF_RW + t * NN + tid] = rwn;
            rwprev = rwn;
            if (tid < MM) {
                float rv = 0.0f;
                #pragma unroll
                for (int w = 0; w < 16; ++w) rv += wmat[w][tid];
                rv *= inv;
                sh_r[tid] = rv;
                out[OFF_R + t * MM + tid] = rv;
            }
        }
        __syncthreads();  // 9
        // ===== K: output projection =====
        if (tid < LL) {
            const float4* r4p = (const float4*)sh_r;
            float a0 = 0.0f, a1 = 0.0f;
            #pragma unroll
            for (int i4 = 0; i4 < 16; ++i4) {
                float4 r = r4p[i4];
                a0 += r.x * sh_Wo[(4*i4) * LL + tid]   + r.y * sh_Wo[(4*i4+1) * LL + tid];
                a1 += r.z * sh_Wo[(4*i4+2) * LL + tid] + r.w * sh_Wo[(4*i4+3) * LL + tid];
            }
            float acc = sh_bo[tid] + a0 + a1;
            out[OFF_SEQ + t * LL + tid] = fminf(fmaxf(acc, 0.0f), 1.0f);
        }
        // no barrier: next phase A reads only sh_r (stable until next J)
    }
}

extern "C" void kernel_launch(void* const* d_in, const int* in_sizes, int n_in,
                              void* d_out, int out_size, void* d_ws, size_t ws_size,
                              hipStream_t stream) {
    const float* seq = (const float*)d_in[0];
    const float* Wc  = (const float*)d_in[1];
    const float* bc  = (const float*)d_in[2];
    const float* Wr  = (const float*)d_in[3];
    const float* br  = (const float*)d_in[4];
    const float* Ww  = (const float*)d_in[5];
    const float* bw  = (const float*)d_in[6];
    const float* Wo  = (const float*)d_in[7];
    const float* bo  = (const float*)d_in[8];
    float* out = (float*)d_out;

    float* wsf  = (float*)d_ws;
    float* pre  = wsf + WSF_PRE;
    float* Wcat = wsf + WSF_WCAT;

    pre_kernel<<<(TT * CC) / 256, 256, 0, stream>>>(seq, Wc, bc, pre);
    pack_kernel<<<(512 * 272 + 255) / 256, 256, 0, stream>>>(Ww, Wr, Wcat);
    ntm_kernel<<<1, 1024, 0, stream>>>(pre, Wc, Wcat, br, bw, Wo, bo, out);
}

// Round 3
// 165333.130 us; speedup vs baseline: 1.4986x; 1.4986x over previous
//
#include <hip/hip_runtime.h>
#include <math.h>

// Problem constants
#define NN 1024
#define MM 64
#define CC 512
#define LL 64
#define TT 8192
#define EPSF 1e-16f

// Flat output offsets (return order: seq_out, ww_h, rw_h, a_h, r_h)
#define OFF_SEQ 0
#define OFF_WW  (TT*LL)
#define OFF_RW  (OFF_WW + TT*NN)
#define OFF_A   (OFF_RW + TT*NN)
#define OFF_R   (OFF_A + TT*MM)

// d_ws float offsets
#define WSF_PRE   0
#define WSF_M     (TT*CC)
#define WSF_WCAT  (WSF_M + 32768)      // 512*272 packed [Ww | Wr | 0pad]

// LDS-only barrier: drains LDS ops (lgkmcnt) but lets global loads/stores stay in
// flight across the barrier. __syncthreads would force s_waitcnt vmcnt(0) too,
// retiring every in-flight out[] store and prefetch 9x per step. The "memory"
// clobber pins LDS producer writes before / consumer reads after this point.
#define BAR() asm volatile("s_waitcnt lgkmcnt(0)\n\ts_barrier" ::: "memory")

__device__ __forceinline__ float sigmoid_f(float x) { return 1.0f / (1.0f + __expf(-x)); }
__device__ __forceinline__ float softplus_f(float x) { return (x > 15.0f) ? x : __logf(1.0f + __expf(x)); }
__device__ __forceinline__ float tanh_f(float x) { float e = __expf(2.0f * x); return 1.0f - 2.0f / (e + 1.0f); }
__device__ __forceinline__ float pow_f(float b, float g) { return __expf(g * __logf(b)); }  // b >= 0
__device__ __forceinline__ int bitrev4(int l) {
    return ((l & 1) << 3) | ((l & 2) << 1) | ((l & 4) >> 1) | ((l & 8) >> 3);
}

// Kernel 1: pre[t][j] = sum_i seq[t][i] * Wc[i][j] + bc[j]
__global__ void pre_kernel(const float* __restrict__ seq, const float* __restrict__ Wc,
                           const float* __restrict__ bc, float* __restrict__ pre) {
    int gid = blockIdx.x * blockDim.x + threadIdx.x;
    int t = gid >> 9;
    int j = gid & 511;
    if (t >= TT) return;
    const float* s = seq + t * LL;
    float acc = bc[j];
    #pragma unroll 8
    for (int i = 0; i < LL; ++i) acc += s[i] * Wc[i * CC + j];
    pre[gid] = acc;
}

// Kernel 1b: Wcat[512][272] = [Ww (198 cols) | Wr (70 cols) | 4 zero cols]
__global__ void pack_kernel(const float* __restrict__ Ww, const float* __restrict__ Wr,
                            float* __restrict__ Wcat) {
    int gid = blockIdx.x * 256 + threadIdx.x;
    if (gid >= 512 * 272) return;
    int r = gid / 272, c = gid - r * 272;
    float v = 0.0f;
    if (c < 198) v = Ww[r * 198 + c];
    else if (c < 268) v = Wr[r * 70 + (c - 198)];
    Wcat[gid] = v;
}

// Persistent single workgroup. Round-10: revert to the 176ms structure (round-1 minus
// LDS staging; mh persistent, original A/C streaming) + ONE change: LDS-only barriers
// (BAR macro) replacing all 9 in-loop __syncthreads, plus the pre[t+1] prefetch split
// into D-load-to-VGPR / J-ds_write so its L2 latency spans 5 phases instead of being
// vmcnt-drained at barrier 4. Lessons r1/r2: no extra float4 state across barriers
// (spills at the 64-VGPR wall), no launch_bounds min-waves arg.
__global__ __launch_bounds__(1024)
void ntm_kernel(
    const float* __restrict__ pre,   // [TT][CC]
    const float* __restrict__ Wc,    // [128][512]
    const float* __restrict__ Wcat,  // [512][272] packed Ww|Wr
    const float* __restrict__ br,    // [70]
    const float* __restrict__ bw,    // [198]
    const float* __restrict__ Wo,    // [64][64]
    const float* __restrict__ bo,    // [64]
    float* __restrict__ out)
{
    __shared__ __align__(16) float sh_part[4096];     // A: 8x512 ; C: 8x272
    __shared__ __align__(16) float sh_h[CC];
    __shared__ __align__(16) float sh_kw[MM];
    __shared__ __align__(16) float sh_kr[MM];
    __shared__ __align__(16) float sh_e[MM];
    __shared__ __align__(16) float sh_a[MM];
    __shared__ __align__(16) float sh_scal[16];
    __shared__ __align__(16) float sh_evbuf[NN];
    __shared__ __align__(16) float sh_wpbuf[NN];
    __shared__ __align__(16) float red[4][16];
    __shared__ __align__(16) float wmat[16][MM];
    __shared__ __align__(16) float sh_r[MM];
    __shared__ __align__(16) float sh_Wo[MM * LL];
    __shared__ __align__(16) float sh_bo[LL];
    __shared__ __align__(16) float sh_bw[200];
    __shared__ __align__(16) float sh_br[72];
    __shared__ __align__(16) float sh_pren[CC];       // prefetched pre[t+1]

    const int tid  = threadIdx.x;
    const int lane = tid & 63;
    const int wv   = tid >> 6;

    // ---- preload constants into LDS, init state ----
    for (int i = tid; i < MM * LL; i += NN) sh_Wo[i] = Wo[i];
    if (tid < LL)  sh_bo[tid] = bo[tid];
    if (tid < 198) sh_bw[tid] = bw[tid];
    if (tid < 70)  sh_br[tid] = br[tid];
    if (tid < MM)  sh_r[tid] = 1e-6f;
    if (tid < CC)  sh_pren[tid] = pre[tid];

    float Mlo[32];
    #pragma unroll
    for (int j = 0; j < 32; ++j) Mlo[j] = 1e-6f;
    float4 mh[8];
    #pragma unroll
    for (int k = 0; k < 8; ++k) mh[k] = make_float4(1e-6f, 1e-6f, 1e-6f, 1e-6f);
    float rown = sqrtf(64.0f * 1e-12f);
    float wwprev = (tid == NN / 2) ? 1.0f : 0.0f;
    float rwprev = wwprev;
    __syncthreads();   // init barrier: full sync (one-time)

    for (int t = 0; t < TT; ++t) {
        // ===== A: h-partials, float4 col-groups. thread=(g:128 col-groups, q:8 row-chunks) =====
        {
            int g = tid & 127, q = tid >> 7;          // cols 4g..4g+3, rows 8q..8q+7 of Wc2
            const float4* wbase = (const float4*)(Wc + (64 + q * 8) * CC) + g;
            float4 acc = make_float4(0.0f, 0.0f, 0.0f, 0.0f);
            #pragma unroll
            for (int i = 0; i < 8; ++i) {
                float rv = sh_r[q * 8 + i];
                float4 w = wbase[i * 128];            // next row: +512 floats = +128 float4
                acc.x += rv * w.x; acc.y += rv * w.y;
                acc.z += rv * w.z; acc.w += rv * w.w;
            }
            ((float4*)sh_part)[q * 128 + g] = acc;    // sh_part[q*512 + 4g]
        }
        BAR();  // 1
        // ===== B: h = tanh(pre + 8 partials) =====
        if (tid < CC) {
            float p0 = sh_part[tid]          + sh_part[512 + tid];
            float p1 = sh_part[1024 + tid]   + sh_part[1536 + tid];
            float p2 = sh_part[2048 + tid]   + sh_part[2560 + tid];
            float p3 = sh_part[3072 + tid]   + sh_part[3584 + tid];
            float v = sh_pren[tid] + ((p0 + p1) + (p2 + p3));
            sh_h[tid] = tanh_f(v);
        }
        BAR();  // 2
        // ===== C: ow/orr partials, float4 col-groups of Wcat. 544 threads =====
        if (tid < 544) {
            int g = tid % 68, q = tid / 68;           // cols 4g..4g+3, rows 64q..64q+63
            const float4* wbase = (const float4*)(Wcat + (q * 64) * 272) + g;
            float4 acc = make_float4(0.0f, 0.0f, 0.0f, 0.0f);
            #pragma unroll 8
            for (int i = 0; i < 64; ++i) {
                float hv = sh_h[q * 64 + i];
                float4 w = wbase[i * 68];             // next row: +272 floats = +68 float4
                acc.x += hv * w.x; acc.y += hv * w.y;
                acc.z += hv * w.z; acc.w += hv * w.w;
            }
            ((float4*)sh_part)[q * 68 + g] = acc;     // sh_part[q*272 + 4g]
        }
        BAR();  // 3
        // ===== D: head transforms, ow folded inline from 8 partials (+ pre prefetch to reg) =====
        float pren_v = 0.0f;
        #define OWV(c) ( (((sh_part[(c)] + sh_part[272 + (c)]) + (sh_part[544 + (c)] + sh_part[816 + (c)])) \
                        + ((sh_part[1088 + (c)] + sh_part[1360 + (c)]) + (sh_part[1632 + (c)] + sh_part[1904 + (c)]))) \
                        + ((c) < 198 ? sh_bw[(c)] : sh_br[(c) - 198]) )
        if (wv == 0) {
            float v = tanh_f(OWV(lane));
            sh_kw[lane] = v;
            float s2 = v * v;
            #pragma unroll
            for (int m = 1; m < 64; m <<= 1) s2 += __shfl_xor(s2, m, 64);
            if (lane == 0) sh_scal[6] = sqrtf(s2);
        } else if (wv == 1) {
            float v = tanh_f(OWV(198 + lane));
            sh_kr[lane] = v;
            float s2 = v * v;
            #pragma unroll
            for (int m = 1; m < 64; m <<= 1) s2 += __shfl_xor(s2, m, 64);
            if (lane == 0) sh_scal[14] = sqrtf(s2);
        } else if (wv == 2) {
            sh_e[lane] = sigmoid_f(OWV(70 + lane));
        } else if (wv == 3) {
            float v = tanh_f(OWV(134 + lane));
            sh_a[lane] = v;
            out[OFF_A + t * MM + lane] = v;
        } else if (wv == 4) {
            if (lane == 0) {
                sh_scal[0] = softplus_f(OWV(64));
                sh_scal[1] = sigmoid_f(OWV(65));
                float x0 = OWV(66), x1 = OWV(67), x2 = OWV(68);
                float mx = fmaxf(x0, fmaxf(x1, x2));
                float e0 = __expf(x0 - mx), e1 = __expf(x1 - mx), e2 = __expf(x2 - mx);
                float ss = e0 + e1 + e2;
                sh_scal[2] = e0 / ss; sh_scal[3] = e1 / ss; sh_scal[4] = e2 / ss;
                sh_scal[5] = 1.0f + softplus_f(OWV(69));
            }
        } else if (wv == 5) {
            if (lane == 0) {
                sh_scal[8] = softplus_f(OWV(198 + 64));
                sh_scal[9] = sigmoid_f(OWV(198 + 65));
                float x0 = OWV(198 + 66), x1 = OWV(198 + 67), x2 = OWV(198 + 68);
                float mx = fmaxf(x0, fmaxf(x1, x2));
                float e0 = __expf(x0 - mx), e1 = __expf(x1 - mx), e2 = __expf(x2 - mx);
                float ss = e0 + e1 + e2;
                sh_scal[10] = e0 / ss; sh_scal[11] = e1 / ss; sh_scal[12] = e2 / ss;
                sh_scal[13] = 1.0f + softplus_f(OWV(198 + 69));
            }
        } else if (wv >= 6 && wv < 14) {     // prefetch pre[t+1] into a REGISTER (written to LDS in J)
            if (t + 1 < TT) pren_v = pre[(t + 1) * CC + (tid - 384)];
        }
        #undef OWV
        BAR();  // 4

        // ===== E: write-head dot + ev =====
        float betaW = sh_scal[0], gW = sh_scal[1];
        float s0W = sh_scal[2], s1W = sh_scal[3], s2W = sh_scal[4];
        float gamW = sh_scal[5], knW = sh_scal[6];
        {
            const float4* k4 = (const float4*)sh_kw;
            float d0 = 0.0f, d1 = 0.0f, d2 = 0.0f, d3 = 0.0f;
            #pragma unroll
            for (int j4 = 0; j4 < 8; ++j4) {
                float4 k = k4[j4];
                d0 += Mlo[4*j4]   * k.x;
                d1 += Mlo[4*j4+1] * k.y;
                d2 += Mlo[4*j4+2] * k.z;
                d3 += Mlo[4*j4+3] * k.w;
            }
            #pragma unroll
            for (int k8 = 0; k8 < 8; ++k8) {
                float4 k = k4[8 + k8];
                d0 += mh[k8].x * k.x;
                d1 += mh[k8].y * k.y;
                d2 += mh[k8].z * k.z;
                d3 += mh[k8].w * k.w;
            }
            float dot = (d0 + d1) + (d2 + d3);
            float sim = dot / (rown * knW + EPSF);
            float ev = __expf(betaW * sim);
            sh_evbuf[tid] = ev;
            sh_wpbuf[tid] = wwprev;
            float s = ev;
            #pragma unroll
            for (int m = 1; m < 64; m <<= 1) s += __shfl_xor(s, m, 64);
            if (lane == 0) red[0][wv] = s;
        }
        BAR();  // 5
        // ===== F: conv + sharpen (write) =====
        float wshW;
        {
            const float4* rp = (const float4*)red[0];
            float Sev = 0.0f;
            #pragma unroll
            for (int w4 = 0; w4 < 4; ++w4) { float4 p = rp[w4]; Sev += p.x + p.y + p.z + p.w; }
            int tm1 = (tid + NN - 1) & (NN - 1), tp1 = (tid + 1) & (NN - 1);
            float cEV = s0W * sh_evbuf[tm1] + s1W * sh_evbuf[tid] + s2W * sh_evbuf[tp1];
            float cWP = s0W * sh_wpbuf[tm1] + s1W * sh_wpbuf[tid] + s2W * sh_wpbuf[tp1];
            float ws = (gW / Sev) * cEV + (1.0f - gW) * cWP;
            wshW = pow_f(ws, gamW);
            float s = wshW;
            #pragma unroll
            for (int m = 1; m < 64; m <<= 1) s += __shfl_xor(s, m, 64);
            if (lane == 0) red[1][wv] = s;
        }
        BAR();  // 6
        // ===== G: normalize wwn; M update + norm =====
        {
            const float4* rp = (const float4*)red[1];
            float Swsh = 0.0f;
            #pragma unroll
            for (int w4 = 0; w4 < 4; ++w4) { float4 p = rp[w4]; Swsh += p.x + p.y + p.z + p.w; }
            float wwn = wshW / (Swsh + EPSF);
            out[OFF_WW + t * NN + tid] = wwn;
            wwprev = wwn;
            const float4* e4p = (const float4*)sh_e;
            const float4* a4p = (const float4*)sh_a;
            float n0 = 0.0f, n1 = 0.0f, n2 = 0.0f, n3 = 0.0f;
            #pragma unroll
            for (int j4 = 0; j4 < 8; ++j4) {
                float4 e = e4p[j4], a = a4p[j4];
                float m0 = Mlo[4*j4]   * (1.0f - wwn * e.x) + wwn * a.x;
                float m1 = Mlo[4*j4+1] * (1.0f - wwn * e.y) + wwn * a.y;
                float m2 = Mlo[4*j4+2] * (1.0f - wwn * e.z) + wwn * a.z;
                float m3 = Mlo[4*j4+3] * (1.0f - wwn * e.w) + wwn * a.w;
                Mlo[4*j4] = m0; Mlo[4*j4+1] = m1; Mlo[4*j4+2] = m2; Mlo[4*j4+3] = m3;
                n0 += m0 * m0; n1 += m1 * m1; n2 += m2 * m2; n3 += m3 * m3;
            }
            #pragma unroll
            for (int k = 0; k < 8; ++k) {
                float4 e = e4p[8 + k], a = a4p[8 + k];
                float4 m = mh[k];
                m.x = m.x * (1.0f - wwn * e.x) + wwn * a.x;
                m.y = m.y * (1.0f - wwn * e.y) + wwn * a.y;
                m.z = m.z * (1.0f - wwn * e.z) + wwn * a.z;
                m.w = m.w * (1.0f - wwn * e.w) + wwn * a.w;
                mh[k] = m;
                n0 += m.x * m.x; n1 += m.y * m.y; n2 += m.z * m.z; n3 += m.w * m.w;
            }
            rown = sqrtf((n0 + n1) + (n2 + n3));
        }

        // ===== H: read-head dot + ev =====
        float betaR = sh_scal[8], gR = sh_scal[9];
        float s0R = sh_scal[10], s1R = sh_scal[11], s2R = sh_scal[12];
        float gamR = sh_scal[13], knR = sh_scal[14];
        {
            const float4* k4 = (const float4*)sh_kr;
            float d0 = 0.0f, d1 = 0.0f, d2 = 0.0f, d3 = 0.0f;
            #pragma unroll
            for (int j4 = 0; j4 < 8; ++j4) {
                float4 k = k4[j4];
                d0 += Mlo[4*j4]   * k.x;
                d1 += Mlo[4*j4+1] * k.y;
                d2 += Mlo[4*j4+2] * k.z;
                d3 += Mlo[4*j4+3] * k.w;
            }
            #pragma unroll
            for (int k8 = 0; k8 < 8; ++k8) {
                float4 k = k4[8 + k8];
                d0 += mh[k8].x * k.x;
                d1 += mh[k8].y * k.y;
                d2 += mh[k8].z * k.z;
                d3 += mh[k8].w * k.w;
            }
            float dot = (d0 + d1) + (d2 + d3);
            float sim = dot / (rown * knR + EPSF);
            float ev = __expf(betaR * sim);
            sh_evbuf[tid] = ev;
            sh_wpbuf[tid] = rwprev;
            float s = ev;
            #pragma unroll
            for (int m = 1; m < 64; m <<= 1) s += __shfl_xor(s, m, 64);
            if (lane == 0) red[2][wv] = s;
        }
        BAR();  // 7
        // ===== I: conv + sharpen (read); transpose partials =====
        float wshR;
        {
            const float4* rp = (const float4*)red[2];
            float Sev = 0.0f;
            #pragma unroll
            for (int w4 = 0; w4 < 4; ++w4) { float4 p = rp[w4]; Sev += p.x + p.y + p.z + p.w; }
            int tm1 = (tid + NN - 1) & (NN - 1), tp1 = (tid + 1) & (NN - 1);
            float cEV = s0R * sh_evbuf[tm1] + s1R * sh_evbuf[tid] + s2R * sh_evbuf[tp1];
            float cWP = s0R * sh_wpbuf[tm1] + s1R * sh_wpbuf[tid] + s2R * sh_wpbuf[tp1];
            float ws = (gR / Sev) * cEV + (1.0f - gR) * cWP;
            wshR = pow_f(ws, gamR);
            float s = wshR;
            #pragma unroll
            for (int m = 1; m < 64; m <<= 1) s += __shfl_xor(s, m, 64);
            if (lane == 0) red[3][wv] = s;
            #pragma unroll
            for (int chunk = 0; chunk < 4; ++chunk) {
                const int cb = chunk * 16;
                float v[16];
                if (chunk < 2) {
                    #pragma unroll
                    for (int i = 0; i < 16; ++i) v[i] = wshR * Mlo[chunk * 16 + i];
                } else {
                    #pragma unroll
                    for (int k = 0; k < 4; ++k) {
                        float4 m = mh[(chunk - 2) * 4 + k];
                        v[4*k]   = wshR * m.x;
                        v[4*k+1] = wshR * m.y;
                        v[4*k+2] = wshR * m.z;
                        v[4*k+3] = wshR * m.w;
                    }
                }
                #pragma unroll
                for (int st = 0; st < 4; ++st) {
                    const int m = 1 << st;
                    const int hs = 8 >> st;
                    bool hi = (lane & m) != 0;
                    #pragma unroll
                    for (int i = 0; i < 8; ++i) {
                        if (i < hs) {
                            float send = hi ? v[i] : v[i + hs];
                            float recv = __shfl_xor(send, m, 64);
                            float keep = hi ? v[i + hs] : v[i];
                            v[i] = keep + recv;
                        }
                    }
                }
                float v0 = v[0];
                v0 += __shfl_xor(v0, 16, 64);
                v0 += __shfl_xor(v0, 32, 64);
                if (lane < 16) wmat[wv][cb + bitrev4(lane)] = v0;
            }
        }
        BAR();  // 8
        // ===== J: normalize rwn + finalize; commit pre[t+1] prefetch to LDS =====
        {
            if (wv >= 6 && wv < 14 && t + 1 < TT) sh_pren[tid - 384] = pren_v;
            const float4* rp = (const float4*)red[3];
            float Swsh = 0.0f;
            #pragma unroll
            for (int w4 = 0; w4 < 4; ++w4) { float4 p = rp[w4]; Swsh += p.x + p.y + p.z + p.w; }
            float inv = 1.0f / (Swsh + EPSF);
            float rwn = wshR * inv;
            out[OFF_RW + t * NN + tid] = rwn;
            rwprev = rwn;
            if (tid < MM) {
                float rv = 0.0f;
                #pragma unroll
                for (int w = 0; w < 16; ++w) rv += wmat[w][tid];
                rv *= inv;
                sh_r[tid] = rv;
                out[OFF_R + t * MM + tid] = rv;
            }
        }
        BAR();  // 9
        // ===== K: output projection =====
        if (tid < LL) {
            const float4* r4p = (const float4*)sh_r;
            float a0 = 0.0f, a1 = 0.0f;
            #pragma unroll
            for (int i4 = 0; i4 < 16; ++i4) {
                float4 r = r4p[i4];
                a0 += r.x * sh_Wo[(4*i4) * LL + tid]   + r.y * sh_Wo[(4*i4+1) * LL + tid];
                a1 += r.z * sh_Wo[(4*i4+2) * LL + tid] + r.w * sh_Wo[(4*i4+3) * LL + tid];
            }
            float acc = sh_bo[tid] + a0 + a1;
            out[OFF_SEQ + t * LL + tid] = fminf(fmaxf(acc, 0.0f), 1.0f);
        }
        // no barrier: next phase A reads only sh_r (stable until next J)
    }
}

extern "C" void kernel_launch(void* const* d_in, const int* in_sizes, int n_in,
                              void* d_out, int out_size, void* d_ws, size_t ws_size,
                              hipStream_t stream) {
    const float* seq = (const float*)d_in[0];
    const float* Wc  = (const float*)d_in[1];
    const float* bc  = (const float*)d_in[2];
    const float* Wr  = (const float*)d_in[3];
    const float* br  = (const float*)d_in[4];
    const float* Ww  = (const float*)d_in[5];
    const float* bw  = (const float*)d_in[6];
    const float* Wo  = (const float*)d_in[7];
    const float* bo  = (const float*)d_in[8];
    float* out = (float*)d_out;

    float* wsf  = (float*)d_ws;
    float* pre  = wsf + WSF_PRE;
    float* Wcat = wsf + WSF_WCAT;

    pre_kernel<<<(TT * CC) / 256, 256, 0, stream>>>(seq, Wc, bc, pre);
    pack_kernel<<<(512 * 272 + 255) / 256, 256, 0, stream>>>(Ww, Wr, Wcat);
    ntm_kernel<<<1, 1024, 0, stream>>>(pre, Wc, Wcat, br, bw, Wo, bo, out);
}

// Round 5
// 137262.671 us; speedup vs baseline: 1.8050x; 1.2045x over previous
//
#include <hip/hip_runtime.h>
#include <math.h>

// Problem constants
#define NN 1024
#define MM 64
#define CC 512
#define LL 64
#define TT 8192
#define EPSF 1e-16f

// Flat output offsets (return order: seq_out, ww_h, rw_h, a_h, r_h)
#define OFF_SEQ 0
#define OFF_WW  (TT*LL)
#define OFF_RW  (OFF_WW + TT*NN)
#define OFF_A   (OFF_RW + TT*NN)
#define OFF_R   (OFF_A + TT*MM)

// d_ws float offsets
#define WSF_PRE   0
#define WSF_M     (TT*CC)
#define WSF_WCAT  (WSF_M + 32768)      // 512*272 packed [Ww | Wr | 0pad]

// LDS-only barrier (round-3 win, -5%): drains lgkmcnt but lets global ops stay in
// flight across the barrier (no vmcnt drain). "memory" clobber pins LDS ordering.
#define BAR() asm volatile("s_waitcnt lgkmcnt(0)\n\ts_barrier" ::: "memory")

__device__ __forceinline__ float sigmoid_f(float x) { return 1.0f / (1.0f + __expf(-x)); }
__device__ __forceinline__ float softplus_f(float x) { return (x > 15.0f) ? x : __logf(1.0f + __expf(x)); }
__device__ __forceinline__ float tanh_f(float x) { float e = __expf(2.0f * x); return 1.0f - 2.0f / (e + 1.0f); }
__device__ __forceinline__ float pow_f(float b, float g) { return __expf(g * __logf(b)); }  // b >= 0
__device__ __forceinline__ int bitrev4(int l) {
    return ((l & 1) << 3) | ((l & 2) << 1) | ((l & 4) >> 1) | ((l & 8) >> 3);
}

// Cross-lane XOR exchange. m=1,2 on the VALU via DPP quad_perm (unambiguous,
// standard semantics); m=4,8,16,32 via __shfl_xor (DS pipe, proven correct).
// Round-4 ERRATUM: v_permlane32_swap_b32 swaps lanes[0:31] of vdst with
// lanes[32:63] of src — my hi/lo select was inverted, making xor(32) the
// identity. Reverted m=32 to shfl_xor; do not reintroduce without an
// assembly-verified probe.
__device__ __forceinline__ float xor_any(float v, const int m, const int lane) {
    if (m == 1)
        return __int_as_float(__builtin_amdgcn_mov_dpp(__float_as_int(v), 0xB1, 0xF, 0xF, true)); // quad_perm [1,0,3,2]
    if (m == 2)
        return __int_as_float(__builtin_amdgcn_mov_dpp(__float_as_int(v), 0x4E, 0xF, 0xF, true)); // quad_perm [2,3,0,1]
    return __shfl_xor(v, m, 64);
}

// Full-wave butterfly sum (all lanes get total). Same add order as the old
// shfl_xor loop; only the transport pipe for m=1,2 differs.
__device__ __forceinline__ float bfly64(float s, const int lane) {
    s += xor_any(s, 1, lane);
    s += xor_any(s, 2, lane);
    s += xor_any(s, 4, lane);
    s += xor_any(s, 8, lane);
    s += xor_any(s, 16, lane);
    s += xor_any(s, 32, lane);
    return s;
}

// Kernel 1: pre[t][j] = sum_i seq[t][i] * Wc[i][j] + bc[j]
__global__ void pre_kernel(const float* __restrict__ seq, const float* __restrict__ Wc,
                           const float* __restrict__ bc, float* __restrict__ pre) {
    int gid = blockIdx.x * blockDim.x + threadIdx.x;
    int t = gid >> 9;
    int j = gid & 511;
    if (t >= TT) return;
    const float* s = seq + t * LL;
    float acc = bc[j];
    #pragma unroll 8
    for (int i = 0; i < LL; ++i) acc += s[i] * Wc[i * CC + j];
    pre[gid] = acc;
}

// Kernel 1b: Wcat[512][272] = [Ww (198 cols) | Wr (70 cols) | 4 zero cols]
__global__ void pack_kernel(const float* __restrict__ Ww, const float* __restrict__ Wr,
                            float* __restrict__ Wcat) {
    int gid = blockIdx.x * 256 + threadIdx.x;
    if (gid >= 512 * 272) return;
    int r = gid / 272, c = gid - r * 272;
    float v = 0.0f;
    if (c < 198) v = Ww[r * 198 + c];
    else if (c < 268) v = Wr[r * 70 + (c - 198)];
    Wcat[gid] = v;
}

// Persistent single workgroup. Round-12 = round-11 structure with the permlane
// erratum fixed (m=32 back on shfl_xor):
//  - DPP quad_perm for m=1,2 exchanges (DS-pipe -> VALU-pipe; 12 of 17 transpose
//    exchange ops per chunk, 2 of 6 per reduction butterfly).
//  - float4 LDS reads in A (sh_r) and C (sh_h).
//  - K (output projection) runs in phase D on idle wave 15, one step late,
//    reading transposed sh_WoT; epilogue K after the loop. Removes wave0's
//    serial J->K->A straggler path at barrier 1.
__global__ __launch_bounds__(1024)
void ntm_kernel(
    const float* __restrict__ pre,   // [TT][CC]
    const float* __restrict__ Wc,    // [128][512]
    const float* __restrict__ Wcat,  // [512][272] packed Ww|Wr
    const float* __restrict__ br,    // [70]
    const float* __restrict__ bw,    // [198]
    const float* __restrict__ Wo,    // [64][64]
    const float* __restrict__ bo,    // [64]
    float* __restrict__ out)
{
    __shared__ __align__(16) float sh_part[4096];     // A: 8x512 ; C: 8x272
    __shared__ __align__(16) float sh_h[CC];
    __shared__ __align__(16) float sh_kw[MM];
    __shared__ __align__(16) float sh_kr[MM];
    __shared__ __align__(16) float sh_e[MM];
    __shared__ __align__(16) float sh_a[MM];
    __shared__ __align__(16) float sh_scal[16];
    __shared__ __align__(16) float sh_evbuf[NN];
    __shared__ __align__(16) float sh_wpbuf[NN];
    __shared__ __align__(16) float red[4][16];
    __shared__ __align__(16) float wmat[16][MM];
    __shared__ __align__(16) float sh_r[MM];
    __shared__ __align__(16) float sh_WoT[LL * MM];   // transposed: [out_col][in_row]
    __shared__ __align__(16) float sh_bo[LL];
    __shared__ __align__(16) float sh_bw[200];
    __shared__ __align__(16) float sh_br[72];
    __shared__ __align__(16) float sh_pren[CC];       // prefetched pre[t+1]

    const int tid  = threadIdx.x;
    const int lane = tid & 63;
    const int wv   = tid >> 6;

    // ---- preload constants into LDS, init state ----
    for (int idx = tid; idx < MM * LL; idx += NN) {
        int i = idx >> 6, o = idx & 63;               // Wo[i][o] -> WoT[o][i]
        sh_WoT[o * MM + i] = Wo[i * LL + o];
    }
    if (tid < LL)  sh_bo[tid] = bo[tid];
    if (tid < 198) sh_bw[tid] = bw[tid];
    if (tid < 70)  sh_br[tid] = br[tid];
    if (tid < MM)  sh_r[tid] = 1e-6f;
    if (tid < CC)  sh_pren[tid] = pre[tid];

    float Mlo[32];
    #pragma unroll
    for (int j = 0; j < 32; ++j) Mlo[j] = 1e-6f;
    float4 mh[8];
    #pragma unroll
    for (int k = 0; k < 8; ++k) mh[k] = make_float4(1e-6f, 1e-6f, 1e-6f, 1e-6f);
    float rown = sqrtf(64.0f * 1e-12f);
    float wwprev = (tid == NN / 2) ? 1.0f : 0.0f;
    float rwprev = wwprev;
    __syncthreads();   // init barrier: full sync (one-time)

    for (int t = 0; t < TT; ++t) {
        // ===== A: h-partials, float4 col-groups. thread=(g:128 col-groups, q:8 row-chunks) =====
        {
            int g = tid & 127, q = tid >> 7;          // cols 4g..4g+3, rows 8q..8q+7 of Wc2
            const float4* wbase = (const float4*)(Wc + (64 + q * 8) * CC) + g;
            float4 ra = *(const float4*)(sh_r + q * 8);
            float4 rb = *(const float4*)(sh_r + q * 8 + 4);
            float rv[8] = {ra.x, ra.y, ra.z, ra.w, rb.x, rb.y, rb.z, rb.w};
            float4 acc = make_float4(0.0f, 0.0f, 0.0f, 0.0f);
            #pragma unroll
            for (int i = 0; i < 8; ++i) {
                float4 w = wbase[i * 128];            // next row: +512 floats = +128 float4
                acc.x += rv[i] * w.x; acc.y += rv[i] * w.y;
                acc.z += rv[i] * w.z; acc.w += rv[i] * w.w;
            }
            ((float4*)sh_part)[q * 128 + g] = acc;    // sh_part[q*512 + 4g]
        }
        BAR();  // 1
        // ===== B: h = tanh(pre + 8 partials) =====
        if (tid < CC) {
            float p0 = sh_part[tid]          + sh_part[512 + tid];
            float p1 = sh_part[1024 + tid]   + sh_part[1536 + tid];
            float p2 = sh_part[2048 + tid]   + sh_part[2560 + tid];
            float p3 = sh_part[3072 + tid]   + sh_part[3584 + tid];
            float v = sh_pren[tid] + ((p0 + p1) + (p2 + p3));
            sh_h[tid] = tanh_f(v);
        }
        BAR();  // 2
        // ===== C: ow/orr partials, float4 col-groups of Wcat. 544 threads =====
        if (tid < 544) {
            int g = tid % 68, q = tid / 68;           // cols 4g..4g+3, rows 64q..64q+63
            const float4* wbase = (const float4*)(Wcat + (q * 64) * 272) + g;
            const float4* h4p = (const float4*)(sh_h + q * 64);
            float4 acc = make_float4(0.0f, 0.0f, 0.0f, 0.0f);
            #pragma unroll 2
            for (int i4 = 0; i4 < 16; ++i4) {
                float4 h4 = h4p[i4];
                const float4* wr = wbase + (i4 * 4) * 68;
                float4 w0 = wr[0];
                float4 w1 = wr[68];
                float4 w2 = wr[136];
                float4 w3 = wr[204];
                acc.x += h4.x * w0.x; acc.y += h4.x * w0.y; acc.z += h4.x * w0.z; acc.w += h4.x * w0.w;
                acc.x += h4.y * w1.x; acc.y += h4.y * w1.y; acc.z += h4.y * w1.z; acc.w += h4.y * w1.w;
                acc.x += h4.z * w2.x; acc.y += h4.z * w2.y; acc.z += h4.z * w2.z; acc.w += h4.z * w2.w;
                acc.x += h4.w * w3.x; acc.y += h4.w * w3.y; acc.z += h4.w * w3.z; acc.w += h4.w * w3.w;
            }
            ((float4*)sh_part)[q * 68 + g] = acc;     // sh_part[q*272 + 4g]
        }
        BAR();  // 3
        // ===== D: head transforms (+ pre prefetch; + previous step's K on wave 15) =====
        float pren_v = 0.0f;
        #define OWV(c) ( (((sh_part[(c)] + sh_part[272 + (c)]) + (sh_part[544 + (c)] + sh_part[816 + (c)])) \
                        + ((sh_part[1088 + (c)] + sh_part[1360 + (c)]) + (sh_part[1632 + (c)] + sh_part[1904 + (c)]))) \
                        + ((c) < 198 ? sh_bw[(c)] : sh_br[(c) - 198]) )
        if (wv == 0) {
            float v = tanh_f(OWV(lane));
            sh_kw[lane] = v;
            float s2 = bfly64(v * v, lane);
            if (lane == 0) sh_scal[6] = sqrtf(s2);
        } else if (wv == 1) {
            float v = tanh_f(OWV(198 + lane));
            sh_kr[lane] = v;
            float s2 = bfly64(v * v, lane);
            if (lane == 0) sh_scal[14] = sqrtf(s2);
        } else if (wv == 2) {
            sh_e[lane] = sigmoid_f(OWV(70 + lane));
        } else if (wv == 3) {
            float v = tanh_f(OWV(134 + lane));
            sh_a[lane] = v;
            out[OFF_A + t * MM + lane] = v;
        } else if (wv == 4) {
            if (lane == 0) {
                sh_scal[0] = softplus_f(OWV(64));
                sh_scal[1] = sigmoid_f(OWV(65));
                float x0 = OWV(66), x1 = OWV(67), x2 = OWV(68);
                float mx = fmaxf(x0, fmaxf(x1, x2));
                float e0 = __expf(x0 - mx), e1 = __expf(x1 - mx), e2 = __expf(x2 - mx);
                float ss = e0 + e1 + e2;
                sh_scal[2] = e0 / ss; sh_scal[3] = e1 / ss; sh_scal[4] = e2 / ss;
                sh_scal[5] = 1.0f + softplus_f(OWV(69));
            }
        } else if (wv == 5) {
            if (lane == 0) {
                sh_scal[8] = softplus_f(OWV(198 + 64));
                sh_scal[9] = sigmoid_f(OWV(198 + 65));
                float x0 = OWV(198 + 66), x1 = OWV(198 + 67), x2 = OWV(198 + 68);
                float mx = fmaxf(x0, fmaxf(x1, x2));
                float e0 = __expf(x0 - mx), e1 = __expf(x1 - mx), e2 = __expf(x2 - mx);
                float ss = e0 + e1 + e2;
                sh_scal[10] = e0 / ss; sh_scal[11] = e1 / ss; sh_scal[12] = e2 / ss;
                sh_scal[13] = 1.0f + softplus_f(OWV(198 + 69));
            }
        } else if (wv >= 6 && wv < 14) {     // prefetch pre[t+1] into a REGISTER (written to LDS in J)
            if (t + 1 < TT) pren_v = pre[(t + 1) * CC + (tid - 384)];
        } else if (wv == 15) {
            // K for step t-1: sh_r (written in J(t-1)) is stable until J(t).
            if (t > 0) {
                const float4* r4p = (const float4*)sh_r;
                const float4* wop = (const float4*)(sh_WoT + lane * MM);
                float a0 = 0.0f, a1 = 0.0f;
                #pragma unroll
                for (int i4 = 0; i4 < 16; ++i4) {
                    float4 r = r4p[i4];
                    float4 w = wop[i4];
                    a0 += r.x * w.x + r.y * w.y;
                    a1 += r.z * w.z + r.w * w.w;
                }
                float acc = sh_bo[lane] + a0 + a1;
                out[OFF_SEQ + (t - 1) * LL + lane] = fminf(fmaxf(acc, 0.0f), 1.0f);
            }
        }
        #undef OWV
        BAR();  // 4

        // ===== E: write-head dot + ev =====
        float betaW = sh_scal[0], gW = sh_scal[1];
        float s0W = sh_scal[2], s1W = sh_scal[3], s2W = sh_scal[4];
        float gamW = sh_scal[5], knW = sh_scal[6];
        {
            const float4* k4 = (const float4*)sh_kw;
            float d0 = 0.0f, d1 = 0.0f, d2 = 0.0f, d3 = 0.0f;
            #pragma unroll
            for (int j4 = 0; j4 < 8; ++j4) {
                float4 k = k4[j4];
                d0 += Mlo[4*j4]   * k.x;
                d1 += Mlo[4*j4+1] * k.y;
                d2 += Mlo[4*j4+2] * k.z;
                d3 += Mlo[4*j4+3] * k.w;
            }
            #pragma unroll
            for (int k8 = 0; k8 < 8; ++k8) {
                float4 k = k4[8 + k8];
                d0 += mh[k8].x * k.x;
                d1 += mh[k8].y * k.y;
                d2 += mh[k8].z * k.z;
                d3 += mh[k8].w * k.w;
            }
            float dot = (d0 + d1) + (d2 + d3);
            float sim = dot / (rown * knW + EPSF);
            float ev = __expf(betaW * sim);
            sh_evbuf[tid] = ev;
            sh_wpbuf[tid] = wwprev;
            float s = bfly64(ev, lane);
            if (lane == 0) red[0][wv] = s;
        }
        BAR();  // 5
        // ===== F: conv + sharpen (write) =====
        float wshW;
        {
            const float4* rp = (const float4*)red[0];
            float Sev = 0.0f;
            #pragma unroll
            for (int w4 = 0; w4 < 4; ++w4) { float4 p = rp[w4]; Sev += p.x + p.y + p.z + p.w; }
            int tm1 = (tid + NN - 1) & (NN - 1), tp1 = (tid + 1) & (NN - 1);
            float cEV = s0W * sh_evbuf[tm1] + s1W * sh_evbuf[tid] + s2W * sh_evbuf[tp1];
            float cWP = s0W * sh_wpbuf[tm1] + s1W * sh_wpbuf[tid] + s2W * sh_wpbuf[tp1];
            float ws = (gW / Sev) * cEV + (1.0f - gW) * cWP;
            wshW = pow_f(ws, gamW);
            float s = bfly64(wshW, lane);
            if (lane == 0) red[1][wv] = s;
        }
        BAR();  // 6
        // ===== G: normalize wwn; M update + norm =====
        {
            const float4* rp = (const float4*)red[1];
            float Swsh = 0.0f;
            #pragma unroll
            for (int w4 = 0; w4 < 4; ++w4) { float4 p = rp[w4]; Swsh += p.x + p.y + p.z + p.w; }
            float wwn = wshW / (Swsh + EPSF);
            out[OFF_WW + t * NN + tid] = wwn;
            wwprev = wwn;
            const float4* e4p = (const float4*)sh_e;
            const float4* a4p = (const float4*)sh_a;
            float n0 = 0.0f, n1 = 0.0f, n2 = 0.0f, n3 = 0.0f;
            #pragma unroll
            for (int j4 = 0; j4 < 8; ++j4) {
                float4 e = e4p[j4], a = a4p[j4];
                float m0 = Mlo[4*j4]   * (1.0f - wwn * e.x) + wwn * a.x;
                float m1 = Mlo[4*j4+1] * (1.0f - wwn * e.y) + wwn * a.y;
                float m2 = Mlo[4*j4+2] * (1.0f - wwn * e.z) + wwn * a.z;
                float m3 = Mlo[4*j4+3] * (1.0f - wwn * e.w) + wwn * a.w;
                Mlo[4*j4] = m0; Mlo[4*j4+1] = m1; Mlo[4*j4+2] = m2; Mlo[4*j4+3] = m3;
                n0 += m0 * m0; n1 += m1 * m1; n2 += m2 * m2; n3 += m3 * m3;
            }
            #pragma unroll
            for (int k = 0; k < 8; ++k) {
                float4 e = e4p[8 + k], a = a4p[8 + k];
                float4 m = mh[k];
                m.x = m.x * (1.0f - wwn * e.x) + wwn * a.x;
                m.y = m.y * (1.0f - wwn * e.y) + wwn * a.y;
                m.z = m.z * (1.0f - wwn * e.z) + wwn * a.z;
                m.w = m.w * (1.0f - wwn * e.w) + wwn * a.w;
                mh[k] = m;
                n0 += m.x * m.x; n1 += m.y * m.y; n2 += m.z * m.z; n3 += m.w * m.w;
            }
            rown = sqrtf((n0 + n1) + (n2 + n3));
        }

        // ===== H: read-head dot + ev =====
        float betaR = sh_scal[8], gR = sh_scal[9];
        float s0R = sh_scal[10], s1R = sh_scal[11], s2R = sh_scal[12];
        float gamR = sh_scal[13], knR = sh_scal[14];
        {
            const float4* k4 = (const float4*)sh_kr;
            float d0 = 0.0f, d1 = 0.0f, d2 = 0.0f, d3 = 0.0f;
            #pragma unroll
            for (int j4 = 0; j4 < 8; ++j4) {
                float4 k = k4[j4];
                d0 += Mlo[4*j4]   * k.x;
                d1 += Mlo[4*j4+1] * k.y;
                d2 += Mlo[4*j4+2] * k.z;
                d3 += Mlo[4*j4+3] * k.w;
            }
            #pragma unroll
            for (int k8 = 0; k8 < 8; ++k8) {
                float4 k = k4[8 + k8];
                d0 += mh[k8].x * k.x;
                d1 += mh[k8].y * k.y;
                d2 += mh[k8].z * k.z;
                d3 += mh[k8].w * k.w;
            }
            float dot = (d0 + d1) + (d2 + d3);
            float sim = dot / (rown * knR + EPSF);
            float ev = __expf(betaR * sim);
            sh_evbuf[tid] = ev;
            sh_wpbuf[tid] = rwprev;
            float s = bfly64(ev, lane);
            if (lane == 0) red[2][wv] = s;
        }
        BAR();  // 7
        // ===== I: conv + sharpen (read); transpose partials =====
        float wshR;
        {
            const float4* rp = (const float4*)red[2];
            float Sev = 0.0f;
            #pragma unroll
            for (int w4 = 0; w4 < 4; ++w4) { float4 p = rp[w4]; Sev += p.x + p.y + p.z + p.w; }
            int tm1 = (tid + NN - 1) & (NN - 1), tp1 = (tid + 1) & (NN - 1);
            float cEV = s0R * sh_evbuf[tm1] + s1R * sh_evbuf[tid] + s2R * sh_evbuf[tp1];
            float cWP = s0R * sh_wpbuf[tm1] + s1R * sh_wpbuf[tid] + s2R * sh_wpbuf[tp1];
            float ws = (gR / Sev) * cEV + (1.0f - gR) * cWP;
            wshR = pow_f(ws, gamR);
            float s = bfly64(wshR, lane);
            if (lane == 0) red[3][wv] = s;
            #pragma unroll
            for (int chunk = 0; chunk < 4; ++chunk) {
                const int cb = chunk * 16;
                float v[16];
                if (chunk < 2) {
                    #pragma unroll
                    for (int i = 0; i < 16; ++i) v[i] = wshR * Mlo[chunk * 16 + i];
                } else {
                    #pragma unroll
                    for (int k = 0; k < 4; ++k) {
                        float4 m = mh[(chunk - 2) * 4 + k];
                        v[4*k]   = wshR * m.x;
                        v[4*k+1] = wshR * m.y;
                        v[4*k+2] = wshR * m.z;
                        v[4*k+3] = wshR * m.w;
                    }
                }
                #pragma unroll
                for (int st = 0; st < 4; ++st) {
                    const int m = 1 << st;
                    const int hs = 8 >> st;
                    bool hi = (lane & m) != 0;
                    #pragma unroll
                    for (int i = 0; i < 8; ++i) {
                        if (i < hs) {
                            float send = hi ? v[i] : v[i + hs];
                            float recv = xor_any(send, m, lane);
                            float keep = hi ? v[i + hs] : v[i];
                            v[i] = keep + recv;
                        }
                    }
                }
                float v0 = v[0];
                v0 += xor_any(v0, 16, lane);
                v0 += xor_any(v0, 32, lane);
                if (lane < 16) wmat[wv][cb + bitrev4(lane)] = v0;
            }
        }
        BAR();  // 8
        // ===== J: normalize rwn + finalize; commit pre[t+1] prefetch to LDS =====
        {
            if (wv >= 6 && wv < 14 && t + 1 < TT) sh_pren[tid - 384] = pren_v;
            const float4* rp = (const float4*)red[3];
            float Swsh = 0.0f;
            #pragma unroll
            for (int w4 = 0; w4 < 4; ++w4) { float4 p = rp[w4]; Swsh += p.x + p.y + p.z + p.w; }
            float inv = 1.0f / (Swsh + EPSF);
            float rwn = wshR * inv;
            out[OFF_RW + t * NN + tid] = rwn;
            rwprev = rwn;
            if (tid < MM) {
                float rv = 0.0f;
                #pragma unroll
                for (int w = 0; w < 16; ++w) rv += wmat[w][tid];
                rv *= inv;
                sh_r[tid] = rv;
                out[OFF_R + t * MM + tid] = rv;
            }
        }
        BAR();  // 9
        // (K for this step runs one step late, in phase D on wave 15)
    }

    // Epilogue: K for t = TT-1 (sh_r still holds r(TT-1))
    if (tid < LL) {
        const float4* r4p = (const float4*)sh_r;
        const float4* wop = (const float4*)(sh_WoT + tid * MM);
        float a0 = 0.0f, a1 = 0.0f;
        #pragma unroll
        for (int i4 = 0; i4 < 16; ++i4) {
            float4 r = r4p[i4];
            float4 w = wop[i4];
            a0 += r.x * w.x + r.y * w.y;
            a1 += r.z * w.z + r.w * w.w;
        }
        float acc = sh_bo[tid] + a0 + a1;
        out[OFF_SEQ + (TT - 1) * LL + tid] = fminf(fmaxf(acc, 0.0f), 1.0f);
    }
}

extern "C" void kernel_launch(void* const* d_in, const int* in_sizes, int n_in,
                              void* d_out, int out_size, void* d_ws, size_t ws_size,
                              hipStream_t stream) {
    const float* seq = (const float*)d_in[0];
    const float* Wc  = (const float*)d_in[1];
    const float* bc  = (const float*)d_in[2];
    const float* Wr  = (const float*)d_in[3];
    const float* br  = (const float*)d_in[4];
    const float* Ww  = (const float*)d_in[5];
    const float* bw  = (const float*)d_in[6];
    const float* Wo  = (const float*)d_in[7];
    const float* bo  = (const float*)d_in[8];
    float* out = (float*)d_out;

    float* wsf  = (float*)d_ws;
    float* pre  = wsf + WSF_PRE;
    float* Wcat = wsf + WSF_WCAT;

    pre_kernel<<<(TT * CC) / 256, 256, 0, stream>>>(seq, Wc, bc, pre);
    pack_kernel<<<(512 * 272 + 255) / 256, 256, 0, stream>>>(Ww, Wr, Wcat);
    ntm_kernel<<<1, 1024, 0, stream>>>(pre, Wc, Wcat, br, bw, Wo, bo, out);
}